// Round 1
// baseline (720.772 us; speedup 1.0000x reference)
//
#include <hip/hip_runtime.h>
#include <stdint.h>

// ---- JAX PRNG layout switch -------------------------------------------------
// 1 = modern JAX (jax_threefry_partitionable=True, default since ~0.4.36):
//     split: key_i = threefry(key, (0, i)) ; bits[f] = w0^w1 of threefry(k,(0,f))
// 0 = legacy layout: split pairs (0,2),(1,3) mixed-words; bits pairs (f, f+half)
#define JAX_PARTITIONABLE 1

constexpr int N = 4096;
constexpr int DIM = 64;
constexpr int TOPK = 5;
constexpr int NEGS = 20;
constexpr float TAU_ = 0.1f;
constexpr uint32_t SPAN = 4091u;   // N - TOPK
constexpr uint32_t MULT = 2309u;   // ((1<<16) % SPAN)^2 % SPAN

__device__ __forceinline__ uint32_t rotl32(uint32_t v, int d) {
  return (v << d) | (v >> (32 - d));
}

// Threefry-2x32, 20 rounds, exactly as jax/_src/prng.py lowering.
__device__ __forceinline__ void threefry(uint32_t k0, uint32_t k1,
                                         uint32_t& x0, uint32_t& x1) {
  const uint32_t k2 = k0 ^ k1 ^ 0x1BD11BDAu;
  x0 += k0; x1 += k1;
#define TF_R(r) { x0 += x1; x1 = rotl32(x1, r); x1 ^= x0; }
  TF_R(13) TF_R(15) TF_R(26) TF_R(6)
  x0 += k1; x1 += k2 + 1u;
  TF_R(17) TF_R(29) TF_R(16) TF_R(24)
  x0 += k2; x1 += k0 + 2u;
  TF_R(13) TF_R(15) TF_R(26) TF_R(6)
  x0 += k0; x1 += k1 + 3u;
  TF_R(17) TF_R(29) TF_R(16) TF_R(24)
  x0 += k1; x1 += k2 + 4u;
  TF_R(13) TF_R(15) TF_R(26) TF_R(6)
  x0 += k2; x1 += k0 + 5u;
#undef TF_R
}

// jax.random.randint(key(seed), (N,20), 0, SPAN) element at flat index f.
__device__ __forceinline__ uint32_t sample_idx(uint32_t seed, uint32_t f) {
#if JAX_PARTITIONABLE
  uint32_t a0 = 0u, a1 = 0u; threefry(0u, seed, a0, a1);   // k1 = enc(key,(0,0))
  uint32_t b0 = 0u, b1 = 1u; threefry(0u, seed, b0, b1);   // k2 = enc(key,(0,1))
  uint32_t h0 = 0u, h1 = f;  threefry(a0, a1, h0, h1);
  const uint32_t hi = h0 ^ h1;
  uint32_t l0 = 0u, l1 = f;  threefry(b0, b1, l0, l1);
  const uint32_t lo = l0 ^ l1;
#else
  // legacy split: counts [0,1,2,3] -> pairs (0,2),(1,3); k1=(w0a,w0b), k2=(w1a,w1b)
  uint32_t a0 = 0u, a1 = 2u; threefry(0u, seed, a0, a1);   // (w0a, w1a)
  uint32_t c0 = 1u, c1 = 3u; threefry(0u, seed, c0, c1);   // (w0b, w1b)
  const uint32_t HALF = (uint32_t)(N * NEGS / 2);          // 40960
  uint32_t hi, lo;
  if (f < HALF) {
    uint32_t x0 = f, x1 = f + HALF; threefry(a0, c0, x0, x1); hi = x0;
    x0 = f; x1 = f + HALF;          threefry(a1, c1, x0, x1); lo = x0;
  } else {
    uint32_t x0 = f - HALF, x1 = f; threefry(a0, c0, x0, x1); hi = x1;
    x0 = f - HALF; x1 = f;          threefry(a1, c1, x0, x1); lo = x1;
  }
#endif
  return ((hi % SPAN) * MULT + (lo % SPAN)) % SPAN;
}

__device__ __forceinline__ float acosh_dev(float z) {
  // XLA-style: log(z + sqrt((z-1)(z+1))) — stable near z=1
  return logf(z + sqrtf((z - 1.0f) * (z + 1.0f)));
}

// K0: per-row squared norm + 1/(1 - clip(sq)).  grid (N/256, 2), block 256.
__global__ __launch_bounds__(256) void k_sq(const float* __restrict__ Xa,
                                            const float* __restrict__ Xt,
                                            float* __restrict__ ysq,
                                            float* __restrict__ inv) {
  const int m = blockIdx.y;                       // 0 = text, 1 = audio
  const int i = blockIdx.x * 256 + threadIdx.x;
  const float* __restrict__ X = (m == 0) ? Xt : Xa;
  const float4* xr = (const float4*)(X + (size_t)i * DIM);
  float s = 0.0f;
#pragma unroll
  for (int k = 0; k < DIM / 4; ++k) {
    float4 v = xr[k];
    s = fmaf(v.x, v.x, s); s = fmaf(v.y, v.y, s);
    s = fmaf(v.z, v.z, s); s = fmaf(v.w, v.w, s);
  }
  ysq[m * N + i] = s;
  // 1-EPS (1e-9) rounds to 1.0f in f32, so clip at 1.0f (data max ~0.64 anyway)
  inv[m * N + i] = 1.0f / (1.0f - fminf(s, 1.0f));
}

// K1: fused pairwise-z + per-row top-5.  Each block owns 16 rows, streams all
// 4096 cols in 256-wide tiles.  256 threads: rr=tid>>6 (4 row groups of 4),
// cc=tid&63 (64 col groups of 4); 4x4 register micro-tile, K=64 fully staged.
__global__ __launch_bounds__(256) void k_top5(const float* __restrict__ Xa,
                                              const float* __restrict__ Xt,
                                              const float* __restrict__ ysq,
                                              const float* __restrict__ inv,
                                              uint64_t* __restrict__ top5out) {
  const int m = blockIdx.y;
  const float* __restrict__ X = (m == 0) ? Xt : Xa;
  const int tid = threadIdx.x;
  const int rr4 = (tid >> 6) * 4;
  const int cc4 = (tid & 63) * 4;
  const int i0 = blockIdx.x * 16;

  __shared__ float a_t[16][DIM];     // row-major A tile (4 KB)
  __shared__ float b_t[DIM][256];    // k-major B tile  (64 KB)

  // stage A: 16x64 = 1024 floats = 256 float4, fully coalesced
  ((float4*)a_t)[tid] = ((const float4*)(X + (size_t)i0 * DIM))[tid];

  float xsq_r[4], inv_r[4];
#pragma unroll
  for (int q = 0; q < 4; ++q) {
    xsq_r[q] = ysq[m * N + i0 + rr4 + q];
    inv_r[q] = inv[m * N + i0 + rr4 + q];
  }

  uint64_t t5[4][TOPK];
#pragma unroll
  for (int q = 0; q < 4; ++q)
#pragma unroll
    for (int t = 0; t < TOPK; ++t) t5[q][t] = ~0ull;

  for (int jt = 0; jt < N; jt += 256) {
    __syncthreads();
    {  // stage B transposed: thread tid owns column (row of X) jt+tid
      const float* src = X + (size_t)(jt + tid) * DIM;
#pragma unroll
      for (int k = 0; k < DIM; k += 4) {
        float4 v = *(const float4*)(src + k);
        b_t[k + 0][tid] = v.x; b_t[k + 1][tid] = v.y;
        b_t[k + 2][tid] = v.z; b_t[k + 3][tid] = v.w;
      }
    }
    __syncthreads();

    float ysq_c[4], inv_c[4];
#pragma unroll
    for (int s = 0; s < 4; ++s) {
      ysq_c[s] = ysq[m * N + jt + cc4 + s];
      inv_c[s] = inv[m * N + jt + cc4 + s];
    }

    float acc[4][4];
#pragma unroll
    for (int q = 0; q < 4; ++q)
#pragma unroll
      for (int s = 0; s < 4; ++s) acc[q][s] = 0.0f;

#pragma unroll
    for (int k = 0; k < DIM; k += 4) {
      const float4 a0 = *(const float4*)&a_t[rr4 + 0][k];   // broadcast reads
      const float4 a1 = *(const float4*)&a_t[rr4 + 1][k];
      const float4 a2 = *(const float4*)&a_t[rr4 + 2][k];
      const float4 a3 = *(const float4*)&a_t[rr4 + 3][k];
      const float4 b0 = *(const float4*)&b_t[k + 0][cc4];   // stride-1 reads
      const float4 b1 = *(const float4*)&b_t[k + 1][cc4];
      const float4 b2 = *(const float4*)&b_t[k + 2][cc4];
      const float4 b3 = *(const float4*)&b_t[k + 3][cc4];
#define OUTER(AQ, q)                                                          \
      acc[q][0] = fmaf(AQ.x, b0.x, acc[q][0]);                                \
      acc[q][1] = fmaf(AQ.x, b0.y, acc[q][1]);                                \
      acc[q][2] = fmaf(AQ.x, b0.z, acc[q][2]);                                \
      acc[q][3] = fmaf(AQ.x, b0.w, acc[q][3]);                                \
      acc[q][0] = fmaf(AQ.y, b1.x, acc[q][0]);                                \
      acc[q][1] = fmaf(AQ.y, b1.y, acc[q][1]);                                \
      acc[q][2] = fmaf(AQ.y, b1.z, acc[q][2]);                                \
      acc[q][3] = fmaf(AQ.y, b1.w, acc[q][3]);                                \
      acc[q][0] = fmaf(AQ.z, b2.x, acc[q][0]);                                \
      acc[q][1] = fmaf(AQ.z, b2.y, acc[q][1]);                                \
      acc[q][2] = fmaf(AQ.z, b2.z, acc[q][2]);                                \
      acc[q][3] = fmaf(AQ.z, b2.w, acc[q][3]);                                \
      acc[q][0] = fmaf(AQ.w, b3.x, acc[q][0]);                                \
      acc[q][1] = fmaf(AQ.w, b3.y, acc[q][1]);                                \
      acc[q][2] = fmaf(AQ.w, b3.z, acc[q][2]);                                \
      acc[q][3] = fmaf(AQ.w, b3.w, acc[q][3]);
      OUTER(a0, 0) OUTER(a1, 1) OUTER(a2, 2) OUTER(a3, 3)
#undef OUTER
    }

    // epilogue: z + top-5 insert (key = (z_bits<<32)|col : ties -> lower col)
#pragma unroll
    for (int q = 0; q < 4; ++q) {
      const int gi = i0 + rr4 + q;
#pragma unroll
      for (int s = 0; s < 4; ++s) {
        const int gj = jt + cc4 + s;
        const float diff =
            fmaxf(xsq_r[q] + ysq_c[s] - 2.0f * acc[q][s], 0.0f);
        const float z = 1.0f + 2.0f * diff * inv_r[q] * inv_c[s];
        uint64_t key = ((uint64_t)__float_as_uint(z) << 32) | (uint32_t)gj;
        if (gi != gj && key < t5[q][TOPK - 1]) {
#pragma unroll
          for (int t = 0; t < TOPK; ++t) {
            const uint64_t cur = t5[q][t];
            if (key < cur) { t5[q][t] = key; key = cur; }
          }
        }
      }
    }
  }

  // merge 64 col-group lists per row via LDS (alias b_t: 16*64*5*8 = 40 KB)
  __syncthreads();
  uint64_t* mbuf = (uint64_t*)&b_t[0][0];
#pragma unroll
  for (int q = 0; q < 4; ++q)
#pragma unroll
    for (int t = 0; t < TOPK; ++t)
      mbuf[((size_t)(rr4 + q) * 64 + (tid & 63)) * TOPK + t] = t5[q][t];
  __syncthreads();

  if (tid < 16) {
    uint64_t cur[TOPK];
#pragma unroll
    for (int t = 0; t < TOPK; ++t) cur[t] = mbuf[(size_t)tid * 64 * TOPK + t];
    for (int c = 1; c < 64; ++c) {
      for (int t = 0; t < TOPK; ++t) {
        uint64_t key = mbuf[((size_t)tid * 64 + c) * TOPK + t];
        if (key >= cur[TOPK - 1]) break;   // source list sorted ascending
#pragma unroll
        for (int u = 0; u < TOPK; ++u) {
          const uint64_t cv = cur[u];
          if (key < cv) { cur[u] = key; key = cv; }
        }
      }
    }
#pragma unroll
    for (int t = 0; t < TOPK; ++t)
      top5out[((size_t)m * N + i0 + tid) * TOPK + t] = cur[t];
  }
}

// K2: per-row pos_term + threefry sampling + negative distances + logsumexp.
// grid (N, 2), one wave per row.
__global__ __launch_bounds__(64) void k_neg(const float* __restrict__ Xa,
                                            const float* __restrict__ Xt,
                                            const float* __restrict__ ysq,
                                            const float* __restrict__ inv,
                                            const uint64_t* __restrict__ top5in,
                                            float* __restrict__ rowres) {
  const int m = blockIdx.y;
  const int i = blockIdx.x;
  const float* __restrict__ X = (m == 0) ? Xt : Xa;
  const uint32_t seed = (m == 0) ? 1u : 2u;  // key(1)=text, key(2)=audio
  const int lane = threadIdx.x;

  __shared__ float4 xi4[DIM / 4];
  if (lane < DIM / 4) xi4[lane] = ((const float4*)(X + (size_t)i * DIM))[lane];
  __syncthreads();

  float zt[TOPK];
  uint32_t pidx[TOPK];
#pragma unroll
  for (int t = 0; t < TOPK; ++t) {
    const uint64_t v = top5in[((size_t)m * N + i) * TOPK + t];
    zt[t] = __uint_as_float((uint32_t)(v >> 32));
    pidx[t] = (uint32_t)(v & 0xffffffffu);
  }

  // pos_term = logsumexp(-acosh(z)/tau) over top-5
  float vt[TOPK], vm = -1e30f;
#pragma unroll
  for (int t = 0; t < TOPK; ++t) {
    vt[t] = -acosh_dev(zt[t]) / TAU_;
    vm = fmaxf(vm, vt[t]);
  }
  float ps = 0.0f;
#pragma unroll
  for (int t = 0; t < TOPK; ++t) ps += expf(vt[t] - vm);
  const float pos = vm + logf(ps);

  // sort masked indices ascending (9-comparator network, static indices only)
#define CSWAP(a, b)                                                           \
  { const uint32_t mn = pidx[a] < pidx[b] ? pidx[a] : pidx[b];                \
    const uint32_t mx = pidx[a] < pidx[b] ? pidx[b] : pidx[a];                \
    pidx[a] = mn; pidx[b] = mx; }
  CSWAP(0, 1) CSWAP(3, 4) CSWAP(2, 4) CSWAP(2, 3) CSWAP(1, 4)
  CSWAP(0, 3) CSWAP(0, 2) CSWAP(1, 3) CSWAP(1, 2)
#undef CSWAP

  float v = -1e30f;
  if (lane < NEGS) {
    const uint32_t f = (uint32_t)i * (uint32_t)NEGS + (uint32_t)lane;
    uint32_t c = sample_idx(seed, f);
#pragma unroll
    for (int t = 0; t < TOPK; ++t) c += (c >= pidx[t]) ? 1u : 0u;
    if (c != (uint32_t)i) {  // diagonal: dist=inf -> contributes 0
      const float4* xc = (const float4*)(X + (size_t)c * DIM);
      float dot = 0.0f;
#pragma unroll
      for (int k = 0; k < DIM / 4; ++k) {
        const float4 a = xi4[k];
        const float4 b = xc[k];
        dot = fmaf(a.x, b.x, dot); dot = fmaf(a.y, b.y, dot);
        dot = fmaf(a.z, b.z, dot); dot = fmaf(a.w, b.w, dot);
      }
      const float diff =
          fmaxf(ysq[m * N + i] + ysq[m * N + c] - 2.0f * dot, 0.0f);
      const float z = 1.0f + 2.0f * diff * inv[m * N + i] * inv[m * N + c];
      v = -acosh_dev(z) / TAU_;
    }
  }

  // wave-wide logsumexp over the 20 sample lanes (others contribute exp->0)
  float vmax = v;
#pragma unroll
  for (int o = 32; o > 0; o >>= 1) vmax = fmaxf(vmax, __shfl_xor(vmax, o, 64));
  float e = expf(v - vmax);
  float ss = e;
#pragma unroll
  for (int o = 32; o > 0; o >>= 1) ss += __shfl_xor(ss, o, 64);
  if (lane == 0) rowres[m * N + i] = (vmax + logf(ss)) - pos;
}

// K3: deterministic final reduce (f64 accumulation), out = 0.01 * sum / 4096
__global__ __launch_bounds__(256) void k_reduce(const float* __restrict__ rowres,
                                                float* __restrict__ out) {
  __shared__ double sh[256];
  double s = 0.0;
  for (int idx = threadIdx.x; idx < 2 * N; idx += 256) s += (double)rowres[idx];
  sh[threadIdx.x] = s;
  __syncthreads();
  for (int o = 128; o > 0; o >>= 1) {
    if (threadIdx.x < o) sh[threadIdx.x] += sh[threadIdx.x + o];
    __syncthreads();
  }
  if (threadIdx.x == 0) out[0] = (float)(0.01 * (sh[0] / (double)N));
}

extern "C" void kernel_launch(void* const* d_in, const int* in_sizes, int n_in,
                              void* d_out, int out_size, void* d_ws,
                              size_t ws_size, hipStream_t stream) {
  const float* Xa = (const float*)d_in[0];   // audio_embeds
  const float* Xt = (const float*)d_in[1];   // text_embeds
  float* out = (float*)d_out;

  // ws layout (416 KB total): ysq[2N] | inv[2N] | top5[2N*5 u64] | rowres[2N]
  float* ysq = (float*)d_ws;
  float* inv = ysq + 2 * N;
  uint64_t* top5 = (uint64_t*)(inv + 2 * N);
  float* rowres = (float*)(top5 + (size_t)2 * N * TOPK);

  k_sq<<<dim3(N / 256, 2), 256, 0, stream>>>(Xa, Xt, ysq, inv);
  k_top5<<<dim3(N / 16, 2), 256, 0, stream>>>(Xa, Xt, ysq, inv, top5);
  k_neg<<<dim3(N, 2), 64, 0, stream>>>(Xa, Xt, ysq, inv, top5, rowres);
  k_reduce<<<1, 256, 0, stream>>>(rowres, out);
}

// Round 2
// 180.644 us; speedup vs baseline: 3.9900x; 3.9900x over previous
//
#include <hip/hip_runtime.h>
#include <stdint.h>

#define JAX_PARTITIONABLE 1

constexpr int N = 4096;
constexpr int DIM = 64;
constexpr int TOPK = 5;
constexpr int NEGS = 20;
constexpr float TAU_ = 0.1f;
constexpr uint32_t SPAN = 4091u;   // N - TOPK
constexpr uint32_t MULT = 2309u;   // ((1<<16) % SPAN)^2 % SPAN

__device__ __forceinline__ uint32_t rotl32(uint32_t v, int d) {
  return (v << d) | (v >> (32 - d));
}

// Threefry-2x32, 20 rounds, exactly as jax/_src/prng.py lowering.
__device__ __forceinline__ void threefry(uint32_t k0, uint32_t k1,
                                         uint32_t& x0, uint32_t& x1) {
  const uint32_t k2 = k0 ^ k1 ^ 0x1BD11BDAu;
  x0 += k0; x1 += k1;
#define TF_R(r) { x0 += x1; x1 = rotl32(x1, r); x1 ^= x0; }
  TF_R(13) TF_R(15) TF_R(26) TF_R(6)
  x0 += k1; x1 += k2 + 1u;
  TF_R(17) TF_R(29) TF_R(16) TF_R(24)
  x0 += k2; x1 += k0 + 2u;
  TF_R(13) TF_R(15) TF_R(26) TF_R(6)
  x0 += k0; x1 += k1 + 3u;
  TF_R(17) TF_R(29) TF_R(16) TF_R(24)
  x0 += k1; x1 += k2 + 4u;
  TF_R(13) TF_R(15) TF_R(26) TF_R(6)
  x0 += k2; x1 += k0 + 5u;
#undef TF_R
}

__device__ __forceinline__ uint32_t sample_idx(uint32_t seed, uint32_t f) {
#if JAX_PARTITIONABLE
  uint32_t a0 = 0u, a1 = 0u; threefry(0u, seed, a0, a1);   // k1 = enc(key,(0,0))
  uint32_t b0 = 0u, b1 = 1u; threefry(0u, seed, b0, b1);   // k2 = enc(key,(0,1))
  uint32_t h0 = 0u, h1 = f;  threefry(a0, a1, h0, h1);
  const uint32_t hi = h0 ^ h1;
  uint32_t l0 = 0u, l1 = f;  threefry(b0, b1, l0, l1);
  const uint32_t lo = l0 ^ l1;
#else
  uint32_t a0 = 0u, a1 = 2u; threefry(0u, seed, a0, a1);
  uint32_t c0 = 1u, c1 = 3u; threefry(0u, seed, c0, c1);
  const uint32_t HALF = (uint32_t)(N * NEGS / 2);
  uint32_t hi, lo;
  if (f < HALF) {
    uint32_t x0 = f, x1 = f + HALF; threefry(a0, c0, x0, x1); hi = x0;
    x0 = f; x1 = f + HALF;          threefry(a1, c1, x0, x1); lo = x0;
  } else {
    uint32_t x0 = f - HALF, x1 = f; threefry(a0, c0, x0, x1); hi = x1;
    x0 = f - HALF; x1 = f;          threefry(a1, c1, x0, x1); lo = x1;
  }
#endif
  return ((hi % SPAN) * MULT + (lo % SPAN)) % SPAN;
}

__device__ __forceinline__ float acosh_dev(float z) {
  return logf(z + sqrtf((z - 1.0f) * (z + 1.0f)));
}

// K_pre: per-64-row block: squared norms + inv, and transpose X -> XT[64][N].
__global__ __launch_bounds__(256) void k_pre(const float* __restrict__ Xa,
                                             const float* __restrict__ Xt,
                                             float* __restrict__ XT,
                                             float* __restrict__ ysq,
                                             float* __restrict__ inv) {
  const int m = blockIdx.y;                  // 0 = text, 1 = audio
  const float* __restrict__ X = (m == 0) ? Xt : Xa;
  float* __restrict__ XTm = XT + (size_t)m * DIM * N;
  const int i0 = blockIdx.x * 64;
  const int tid = threadIdx.x;

  __shared__ float t[64][68];                // padded tile

  {  // stage 64 rows x 64 cols, coalesced
    const int r = tid >> 2;
    const int c0 = (tid & 3) * 16;
#pragma unroll
    for (int u = 0; u < 4; ++u)
      *(float4*)&t[r][c0 + 4 * u] =
          *(const float4*)(X + (size_t)(i0 + r) * DIM + c0 + 4 * u);
  }
  __syncthreads();

  if (tid < 64) {  // row norms (same accumulation order as before: k ascending)
    float s = 0.0f;
#pragma unroll
    for (int u = 0; u < 16; ++u) {
      float4 v = *(const float4*)&t[tid][4 * u];
      s = fmaf(v.x, v.x, s); s = fmaf(v.y, v.y, s);
      s = fmaf(v.z, v.z, s); s = fmaf(v.w, v.w, s);
    }
    ysq[m * N + i0 + tid] = s;
    inv[m * N + i0 + tid] = 1.0f / (1.0f - fminf(s, 1.0f));
  }

  {  // transpose out, coalesced: lanes 0..3 cover 64 consecutive i per k-group
    const int k = tid >> 2;
    const int ib = (tid & 3) * 16;
#pragma unroll
    for (int u = 0; u < 4; ++u) {
      const int j = ib + 4 * u;
      float4 v = { t[j][k], t[j + 1][k], t[j + 2][k], t[j + 3][k] };
      *(float4*)&XTm[(size_t)k * N + i0 + j] = v;
    }
  }
}

// K1: fused pairwise-z + per-row top-5.
// Block: 256 threads, 16 rows, streams 256-col B tiles (16 tiles).
// Micro-tile 2 rows x 8 cols: rg = tid>>5 (8 groups x 2 rows), cg = tid&31.
__global__ __launch_bounds__(256) void k_top5(const float* __restrict__ Xa,
                                              const float* __restrict__ Xt,
                                              const float* __restrict__ XT,
                                              const float* __restrict__ ysq,
                                              const float* __restrict__ inv,
                                              uint64_t* __restrict__ top5out) {
  const int m = blockIdx.y;
  const float* __restrict__ X = (m == 0) ? Xt : Xa;
  const float* __restrict__ XTm = XT + (size_t)m * DIM * N;
  const int mN = m * N;
  const int tid = threadIdx.x;
  const int r0 = (tid >> 5) * 2;       // local rows r0, r0+1
  const int c8 = (tid & 31) * 8;       // 8 cols starting here
  const int i0 = blockIdx.x * 16;

  __shared__ float a_t[16][68];        // padded A tile (4.3 KB)
  __shared__ float b_t[64][256];       // k-major B tile (64 KB), aliased later
  __shared__ float ysq_s[256], inv_s[256];

  {  // stage A once (coalesced; lanes 0..15 cover one row)
    const int r = tid >> 4, c4 = (tid & 15) * 4;
    *(float4*)&a_t[r][c4] = *(const float4*)(X + (size_t)(i0 + r) * DIM + c4);
  }

  float xsq_r[2], inv_r[2];
#pragma unroll
  for (int q = 0; q < 2; ++q) {
    xsq_r[q] = ysq[mN + i0 + r0 + q];
    inv_r[q] = inv[mN + i0 + r0 + q];
  }

  uint64_t t5[2][TOPK];
#pragma unroll
  for (int q = 0; q < 2; ++q)
#pragma unroll
    for (int t = 0; t < TOPK; ++t) t5[q][t] = ~0ull;

#pragma unroll 1
  for (int jt = 0; jt < N; jt += 256) {
    __syncthreads();
    {  // stage B tile from XT: straight coalesced copy, no transpose
#pragma unroll
      for (int u = 0; u < 16; ++u) {
        const int k = (tid >> 6) + u * 4;
        *(float4*)&b_t[k][(tid & 63) * 4] =
            *(const float4*)&XTm[(size_t)k * N + jt + (tid & 63) * 4];
      }
      if (tid < 64)
        *(float4*)&ysq_s[tid * 4] = *(const float4*)&ysq[mN + jt + tid * 4];
      else if (tid < 128)
        *(float4*)&inv_s[(tid - 64) * 4] =
            *(const float4*)&inv[mN + jt + (tid - 64) * 4];
    }
    __syncthreads();

    float acc[2][8];
#pragma unroll
    for (int q = 0; q < 2; ++q)
#pragma unroll
      for (int s = 0; s < 8; ++s) acc[q][s] = 0.0f;

#pragma unroll 2
    for (int k4 = 0; k4 < DIM; k4 += 4) {
      const float4 aA = *(const float4*)&a_t[r0][k4];       // broadcast reads
      const float4 aB = *(const float4*)&a_t[r0 + 1][k4];
#pragma unroll
      for (int kk = 0; kk < 4; ++kk) {
        const float4 b0 = *(const float4*)&b_t[k4 + kk][c8];
        const float4 b1 = *(const float4*)&b_t[k4 + kk][c8 + 4];
        const float av0 = (kk == 0) ? aA.x : (kk == 1) ? aA.y
                         : (kk == 2) ? aA.z : aA.w;
        const float av1 = (kk == 0) ? aB.x : (kk == 1) ? aB.y
                         : (kk == 2) ? aB.z : aB.w;
        acc[0][0] = fmaf(av0, b0.x, acc[0][0]);
        acc[0][1] = fmaf(av0, b0.y, acc[0][1]);
        acc[0][2] = fmaf(av0, b0.z, acc[0][2]);
        acc[0][3] = fmaf(av0, b0.w, acc[0][3]);
        acc[0][4] = fmaf(av0, b1.x, acc[0][4]);
        acc[0][5] = fmaf(av0, b1.y, acc[0][5]);
        acc[0][6] = fmaf(av0, b1.z, acc[0][6]);
        acc[0][7] = fmaf(av0, b1.w, acc[0][7]);
        acc[1][0] = fmaf(av1, b0.x, acc[1][0]);
        acc[1][1] = fmaf(av1, b0.y, acc[1][1]);
        acc[1][2] = fmaf(av1, b0.z, acc[1][2]);
        acc[1][3] = fmaf(av1, b0.w, acc[1][3]);
        acc[1][4] = fmaf(av1, b1.x, acc[1][4]);
        acc[1][5] = fmaf(av1, b1.y, acc[1][5]);
        acc[1][6] = fmaf(av1, b1.z, acc[1][6]);
        acc[1][7] = fmaf(av1, b1.w, acc[1][7]);
      }
    }

    // epilogue: z + top-5 insert (key = (z_bits<<32)|col : ties -> lower col)
#pragma unroll
    for (int q = 0; q < 2; ++q) {
      const int gi = i0 + r0 + q;
#pragma unroll
      for (int s = 0; s < 8; ++s) {
        const int gj = jt + c8 + s;
        const float diff =
            fmaxf(xsq_r[q] + ysq_s[c8 + s] - 2.0f * acc[q][s], 0.0f);
        const float z = 1.0f + 2.0f * diff * inv_r[q] * inv_s[c8 + s];
        uint64_t key = ((uint64_t)__float_as_uint(z) << 32) | (uint32_t)gj;
        if (gi != gj && key < t5[q][TOPK - 1]) {
#pragma unroll
          for (int t = 0; t < TOPK; ++t) {
            const uint64_t cur = t5[q][t];
            if (key < cur) { t5[q][t] = key; key = cur; }
          }
        }
      }
    }
  }

  // merge 32 col-group lists per row via LDS (alias b_t: 16*32*5*8 = 20 KB)
  __syncthreads();
  uint64_t* mbuf = (uint64_t*)&b_t[0][0];
#pragma unroll
  for (int q = 0; q < 2; ++q)
#pragma unroll
    for (int t = 0; t < TOPK; ++t)
      mbuf[((size_t)(r0 + q) * 32 + (tid & 31)) * TOPK + t] = t5[q][t];
  __syncthreads();

  if (tid < 16) {
    uint64_t cur[TOPK];
#pragma unroll
    for (int t = 0; t < TOPK; ++t) cur[t] = mbuf[(size_t)tid * 32 * TOPK + t];
    for (int c = 1; c < 32; ++c) {
      for (int t = 0; t < TOPK; ++t) {
        uint64_t key = mbuf[((size_t)tid * 32 + c) * TOPK + t];
        if (key >= cur[TOPK - 1]) break;   // source list sorted ascending
#pragma unroll
        for (int u = 0; u < TOPK; ++u) {
          const uint64_t cv = cur[u];
          if (key < cv) { cur[u] = key; key = cv; }
        }
      }
    }
#pragma unroll
    for (int t = 0; t < TOPK; ++t)
      top5out[((size_t)m * N + i0 + tid) * TOPK + t] = cur[t];
  }
}

// K2: per-row pos_term + threefry sampling + negative distances + logsumexp.
__global__ __launch_bounds__(64) void k_neg(const float* __restrict__ Xa,
                                            const float* __restrict__ Xt,
                                            const float* __restrict__ ysq,
                                            const float* __restrict__ inv,
                                            const uint64_t* __restrict__ top5in,
                                            float* __restrict__ rowres) {
  const int m = blockIdx.y;
  const int i = blockIdx.x;
  const float* __restrict__ X = (m == 0) ? Xt : Xa;
  const uint32_t seed = (m == 0) ? 1u : 2u;  // key(1)=text, key(2)=audio
  const int lane = threadIdx.x;

  __shared__ float4 xi4[DIM / 4];
  if (lane < DIM / 4) xi4[lane] = ((const float4*)(X + (size_t)i * DIM))[lane];
  __syncthreads();

  float zt[TOPK];
  uint32_t pidx[TOPK];
#pragma unroll
  for (int t = 0; t < TOPK; ++t) {
    const uint64_t v = top5in[((size_t)m * N + i) * TOPK + t];
    zt[t] = __uint_as_float((uint32_t)(v >> 32));
    pidx[t] = (uint32_t)(v & 0xffffffffu);
  }

  float vt[TOPK], vm = -1e30f;
#pragma unroll
  for (int t = 0; t < TOPK; ++t) {
    vt[t] = -acosh_dev(zt[t]) / TAU_;
    vm = fmaxf(vm, vt[t]);
  }
  float ps = 0.0f;
#pragma unroll
  for (int t = 0; t < TOPK; ++t) ps += expf(vt[t] - vm);
  const float pos = vm + logf(ps);

#define CSWAP(a, b)                                                           \
  { const uint32_t mn = pidx[a] < pidx[b] ? pidx[a] : pidx[b];                \
    const uint32_t mx = pidx[a] < pidx[b] ? pidx[b] : pidx[a];                \
    pidx[a] = mn; pidx[b] = mx; }
  CSWAP(0, 1) CSWAP(3, 4) CSWAP(2, 4) CSWAP(2, 3) CSWAP(1, 4)
  CSWAP(0, 3) CSWAP(0, 2) CSWAP(1, 3) CSWAP(1, 2)
#undef CSWAP

  float v = -1e30f;
  if (lane < NEGS) {
    const uint32_t f = (uint32_t)i * (uint32_t)NEGS + (uint32_t)lane;
    uint32_t c = sample_idx(seed, f);
#pragma unroll
    for (int t = 0; t < TOPK; ++t) c += (c >= pidx[t]) ? 1u : 0u;
    if (c != (uint32_t)i) {
      const float4* xc = (const float4*)(X + (size_t)c * DIM);
      float dot = 0.0f;
#pragma unroll
      for (int k = 0; k < DIM / 4; ++k) {
        const float4 a = xi4[k];
        const float4 b = xc[k];
        dot = fmaf(a.x, b.x, dot); dot = fmaf(a.y, b.y, dot);
        dot = fmaf(a.z, b.z, dot); dot = fmaf(a.w, b.w, dot);
      }
      const float diff =
          fmaxf(ysq[m * N + i] + ysq[m * N + c] - 2.0f * dot, 0.0f);
      const float z = 1.0f + 2.0f * diff * inv[m * N + i] * inv[m * N + c];
      v = -acosh_dev(z) / TAU_;
    }
  }

  float vmax = v;
#pragma unroll
  for (int o = 32; o > 0; o >>= 1) vmax = fmaxf(vmax, __shfl_xor(vmax, o, 64));
  float e = expf(v - vmax);
  float ss = e;
#pragma unroll
  for (int o = 32; o > 0; o >>= 1) ss += __shfl_xor(ss, o, 64);
  if (lane == 0) rowres[m * N + i] = (vmax + logf(ss)) - pos;
}

// K3: deterministic final reduce (f64 accumulation), out = 0.01 * mean
__global__ __launch_bounds__(256) void k_reduce(const float* __restrict__ rowres,
                                                float* __restrict__ out) {
  __shared__ double sh[256];
  double s = 0.0;
  for (int idx = threadIdx.x; idx < 2 * N; idx += 256) s += (double)rowres[idx];
  sh[threadIdx.x] = s;
  __syncthreads();
  for (int o = 128; o > 0; o >>= 1) {
    if (threadIdx.x < o) sh[threadIdx.x] += sh[threadIdx.x + o];
    __syncthreads();
  }
  if (threadIdx.x == 0) out[0] = (float)(0.01 * (sh[0] / (double)N));
}

extern "C" void kernel_launch(void* const* d_in, const int* in_sizes, int n_in,
                              void* d_out, int out_size, void* d_ws,
                              size_t ws_size, hipStream_t stream) {
  const float* Xa = (const float*)d_in[0];   // audio_embeds
  const float* Xt = (const float*)d_in[1];   // text_embeds
  float* out = (float*)d_out;

  // ws layout (~2.5 MB): ysq[2N] | inv[2N] | top5[2N*5 u64] | rowres[2N] | XT[2][64][N]
  float* ysq = (float*)d_ws;
  float* inv = ysq + 2 * N;
  uint64_t* top5 = (uint64_t*)(inv + 2 * N);
  float* rowres = (float*)(top5 + (size_t)2 * N * TOPK);
  float* XT = rowres + 2 * N;

  k_pre<<<dim3(N / 64, 2), 256, 0, stream>>>(Xa, Xt, XT, ysq, inv);
  k_top5<<<dim3(N / 16, 2), 256, 0, stream>>>(Xa, Xt, XT, ysq, inv, top5);
  k_neg<<<dim3(N, 2), 64, 0, stream>>>(Xa, Xt, ysq, inv, top5, rowres);
  k_reduce<<<1, 256, 0, stream>>>(rowres, out);
}

// Round 3
// 163.870 us; speedup vs baseline: 4.3984x; 1.1024x over previous
//
#include <hip/hip_runtime.h>
#include <stdint.h>

#define JAX_PARTITIONABLE 1

constexpr int N = 4096;
constexpr int DIM = 64;
constexpr int TOPK = 5;
constexpr int NEGS = 20;
constexpr float TAU_ = 0.1f;
constexpr uint32_t SPAN = 4091u;   // N - TOPK
constexpr uint32_t MULT = 2309u;   // ((1<<16) % SPAN)^2 % SPAN

__device__ __forceinline__ uint32_t rotl32(uint32_t v, int d) {
  return (v << d) | (v >> (32 - d));
}

// Threefry-2x32, 20 rounds, exactly as jax/_src/prng.py lowering.
__device__ __forceinline__ void threefry(uint32_t k0, uint32_t k1,
                                         uint32_t& x0, uint32_t& x1) {
  const uint32_t k2 = k0 ^ k1 ^ 0x1BD11BDAu;
  x0 += k0; x1 += k1;
#define TF_R(r) { x0 += x1; x1 = rotl32(x1, r); x1 ^= x0; }
  TF_R(13) TF_R(15) TF_R(26) TF_R(6)
  x0 += k1; x1 += k2 + 1u;
  TF_R(17) TF_R(29) TF_R(16) TF_R(24)
  x0 += k2; x1 += k0 + 2u;
  TF_R(13) TF_R(15) TF_R(26) TF_R(6)
  x0 += k0; x1 += k1 + 3u;
  TF_R(17) TF_R(29) TF_R(16) TF_R(24)
  x0 += k1; x1 += k2 + 4u;
  TF_R(13) TF_R(15) TF_R(26) TF_R(6)
  x0 += k2; x1 += k0 + 5u;
#undef TF_R
}

__device__ __forceinline__ uint32_t sample_idx(uint32_t seed, uint32_t f) {
#if JAX_PARTITIONABLE
  uint32_t a0 = 0u, a1 = 0u; threefry(0u, seed, a0, a1);   // k1 = enc(key,(0,0))
  uint32_t b0 = 0u, b1 = 1u; threefry(0u, seed, b0, b1);   // k2 = enc(key,(0,1))
  uint32_t h0 = 0u, h1 = f;  threefry(a0, a1, h0, h1);
  const uint32_t hi = h0 ^ h1;
  uint32_t l0 = 0u, l1 = f;  threefry(b0, b1, l0, l1);
  const uint32_t lo = l0 ^ l1;
#else
  uint32_t a0 = 0u, a1 = 2u; threefry(0u, seed, a0, a1);
  uint32_t c0 = 1u, c1 = 3u; threefry(0u, seed, c0, c1);
  const uint32_t HALF = (uint32_t)(N * NEGS / 2);
  uint32_t hi, lo;
  if (f < HALF) {
    uint32_t x0 = f, x1 = f + HALF; threefry(a0, c0, x0, x1); hi = x0;
    x0 = f; x1 = f + HALF;          threefry(a1, c1, x0, x1); lo = x0;
  } else {
    uint32_t x0 = f - HALF, x1 = f; threefry(a0, c0, x0, x1); hi = x1;
    x0 = f - HALF; x1 = f;          threefry(a1, c1, x0, x1); lo = x1;
  }
#endif
  return ((hi % SPAN) * MULT + (lo % SPAN)) % SPAN;
}

__device__ __forceinline__ float acosh_dev(float z) {
  return logf(z + sqrtf((z - 1.0f) * (z + 1.0f)));
}

// K_pre: per-64-row block: squared norms + inv, and transpose X -> XT[64][N].
__global__ __launch_bounds__(256) void k_pre(const float* __restrict__ Xa,
                                             const float* __restrict__ Xt,
                                             float* __restrict__ XT,
                                             float* __restrict__ ysq,
                                             float* __restrict__ inv) {
  const int m = blockIdx.y;                  // 0 = text, 1 = audio
  const float* __restrict__ X = (m == 0) ? Xt : Xa;
  float* __restrict__ XTm = XT + (size_t)m * DIM * N;
  const int i0 = blockIdx.x * 64;
  const int tid = threadIdx.x;

  __shared__ float t[64][68];                // padded tile

  {  // stage 64 rows x 64 cols, coalesced
    const int r = tid >> 2;
    const int c0 = (tid & 3) * 16;
#pragma unroll
    for (int u = 0; u < 4; ++u)
      *(float4*)&t[r][c0 + 4 * u] =
          *(const float4*)(X + (size_t)(i0 + r) * DIM + c0 + 4 * u);
  }
  __syncthreads();

  if (tid < 64) {  // row norms (same accumulation order: k ascending)
    float s = 0.0f;
#pragma unroll
    for (int u = 0; u < 16; ++u) {
      float4 v = *(const float4*)&t[tid][4 * u];
      s = fmaf(v.x, v.x, s); s = fmaf(v.y, v.y, s);
      s = fmaf(v.z, v.z, s); s = fmaf(v.w, v.w, s);
    }
    ysq[m * N + i0 + tid] = s;
    inv[m * N + i0 + tid] = 1.0f / (1.0f - fminf(s, 1.0f));
  }

  {  // transpose out, coalesced
    const int k = tid >> 2;
    const int ib = (tid & 3) * 16;
#pragma unroll
    for (int u = 0; u < 4; ++u) {
      const int j = ib + 4 * u;
      float4 v = { t[j][k], t[j + 1][k], t[j + 2][k], t[j + 3][k] };
      *(float4*)&XTm[(size_t)k * N + i0 + j] = v;
    }
  }
}

// K1: fused pairwise-z + per-row top-5.
// Block: 256 threads, 16 rows, streams 128-col B tiles (32 tiles).
// Micro-tile 2 rows x 4 cols: r0=(tid>>5)*2, cols 4t..4t+3 with t=tid&31.
// Column ownership {4t..4t+3} makes every b_t ds_read_b128 bank-minimal.
__global__ __launch_bounds__(256) void k_top5(const float* __restrict__ Xa,
                                              const float* __restrict__ Xt,
                                              const float* __restrict__ XT,
                                              const float* __restrict__ ysq,
                                              const float* __restrict__ inv,
                                              uint64_t* __restrict__ top5out) {
  const int m = blockIdx.y;
  const float* __restrict__ X = (m == 0) ? Xt : Xa;
  const float* __restrict__ XTm = XT + (size_t)m * DIM * N;
  const int mN = m * N;
  const int tid = threadIdx.x;
  const int r0 = (tid >> 5) * 2;       // local rows r0, r0+1
  const int t = tid & 31;
  const int c4 = t * 4;                // 4 cols starting here
  const int i0 = blockIdx.x * 16;

  __shared__ float a_t[16][68];        // padded A tile (4.3 KB)
  __shared__ float b_t[64][128];       // k-major B tile (32 KB), aliased later
  __shared__ float ysq_s[128], inv_s[128];

  {  // stage A once (coalesced)
    const int r = tid >> 4, ca = (tid & 15) * 4;
    *(float4*)&a_t[r][ca] = *(const float4*)(X + (size_t)(i0 + r) * DIM + ca);
  }

  float xsq_r[2], inv_r[2];
#pragma unroll
  for (int q = 0; q < 2; ++q) {
    xsq_r[q] = ysq[mN + i0 + r0 + q];
    inv_r[q] = inv[mN + i0 + r0 + q];
  }

  uint64_t t5[2][TOPK];
#pragma unroll
  for (int q = 0; q < 2; ++q)
#pragma unroll
    for (int tt = 0; tt < TOPK; ++tt) t5[q][tt] = ~0ull;

#pragma unroll 1
  for (int jt = 0; jt < N; jt += 128) {
    __syncthreads();
    {  // stage B tile from XT: straight coalesced copy
#pragma unroll
      for (int u = 0; u < 8; ++u) {
        const int k = (tid >> 5) + u * 8;
        *(float4*)&b_t[k][c4] = *(const float4*)&XTm[(size_t)k * N + jt + c4];
      }
      if (tid < 32)
        *(float4*)&ysq_s[tid * 4] = *(const float4*)&ysq[mN + jt + tid * 4];
      else if (tid < 64)
        *(float4*)&inv_s[(tid - 32) * 4] =
            *(const float4*)&inv[mN + jt + (tid - 32) * 4];
    }
    __syncthreads();

    float acc[2][4];
#pragma unroll
    for (int q = 0; q < 2; ++q)
#pragma unroll
      for (int s = 0; s < 4; ++s) acc[q][s] = 0.0f;

#pragma unroll 2
    for (int k4 = 0; k4 < DIM; k4 += 4) {
      const float4 aA = *(const float4*)&a_t[r0][k4];       // broadcast reads
      const float4 aB = *(const float4*)&a_t[r0 + 1][k4];
#pragma unroll
      for (int kk = 0; kk < 4; ++kk) {
        const float4 b = *(const float4*)&b_t[k4 + kk][c4]; // bank-minimal
        const float av0 = (kk == 0) ? aA.x : (kk == 1) ? aA.y
                         : (kk == 2) ? aA.z : aA.w;
        const float av1 = (kk == 0) ? aB.x : (kk == 1) ? aB.y
                         : (kk == 2) ? aB.z : aB.w;
        acc[0][0] = fmaf(av0, b.x, acc[0][0]);
        acc[0][1] = fmaf(av0, b.y, acc[0][1]);
        acc[0][2] = fmaf(av0, b.z, acc[0][2]);
        acc[0][3] = fmaf(av0, b.w, acc[0][3]);
        acc[1][0] = fmaf(av1, b.x, acc[1][0]);
        acc[1][1] = fmaf(av1, b.y, acc[1][1]);
        acc[1][2] = fmaf(av1, b.z, acc[1][2]);
        acc[1][3] = fmaf(av1, b.w, acc[1][3]);
      }
    }

    // epilogue: z + top-5 insert (key = (z_bits<<32)|col : ties -> lower col)
#pragma unroll
    for (int q = 0; q < 2; ++q) {
      const int gi = i0 + r0 + q;
#pragma unroll
      for (int s = 0; s < 4; ++s) {
        const int gj = jt + c4 + s;
        const float diff =
            fmaxf(xsq_r[q] + ysq_s[c4 + s] - 2.0f * acc[q][s], 0.0f);
        const float z = 1.0f + 2.0f * diff * inv_r[q] * inv_s[c4 + s];
        uint64_t key = ((uint64_t)__float_as_uint(z) << 32) | (uint32_t)gj;
        if (gi != gj && key < t5[q][TOPK - 1]) {
#pragma unroll
          for (int tt = 0; tt < TOPK; ++tt) {
            const uint64_t cur = t5[q][tt];
            if (key < cur) { t5[q][tt] = key; key = cur; }
          }
        }
      }
    }
  }

  // merge 32 col-group lists per row via LDS (alias b_t: 16*32*5*8 = 20 KB)
  __syncthreads();
  uint64_t* mbuf = (uint64_t*)&b_t[0][0];
#pragma unroll
  for (int q = 0; q < 2; ++q)
#pragma unroll
    for (int tt = 0; tt < TOPK; ++tt)
      mbuf[((size_t)(r0 + q) * 32 + t) * TOPK + tt] = t5[q][tt];
  __syncthreads();

  if (tid < 16) {
    uint64_t cur[TOPK];
#pragma unroll
    for (int tt = 0; tt < TOPK; ++tt)
      cur[tt] = mbuf[(size_t)tid * 32 * TOPK + tt];
    for (int c = 1; c < 32; ++c) {
      for (int tt = 0; tt < TOPK; ++tt) {
        uint64_t key = mbuf[((size_t)tid * 32 + c) * TOPK + tt];
        if (key >= cur[TOPK - 1]) break;   // source list sorted ascending
#pragma unroll
        for (int u = 0; u < TOPK; ++u) {
          const uint64_t cv = cur[u];
          if (key < cv) { cur[u] = key; key = cv; }
        }
      }
    }
#pragma unroll
    for (int tt = 0; tt < TOPK; ++tt)
      top5out[((size_t)m * N + i0 + tid) * TOPK + tt] = cur[tt];
  }
}

// K2: per-row pos_term + threefry sampling + negative distances + logsumexp.
__global__ __launch_bounds__(64) void k_neg(const float* __restrict__ Xa,
                                            const float* __restrict__ Xt,
                                            const float* __restrict__ ysq,
                                            const float* __restrict__ inv,
                                            const uint64_t* __restrict__ top5in,
                                            float* __restrict__ rowres) {
  const int m = blockIdx.y;
  const int i = blockIdx.x;
  const float* __restrict__ X = (m == 0) ? Xt : Xa;
  const uint32_t seed = (m == 0) ? 1u : 2u;  // key(1)=text, key(2)=audio
  const int lane = threadIdx.x;

  __shared__ float4 xi4[DIM / 4];
  if (lane < DIM / 4) xi4[lane] = ((const float4*)(X + (size_t)i * DIM))[lane];
  __syncthreads();

  float zt[TOPK];
  uint32_t pidx[TOPK];
#pragma unroll
  for (int tt = 0; tt < TOPK; ++tt) {
    const uint64_t v = top5in[((size_t)m * N + i) * TOPK + tt];
    zt[tt] = __uint_as_float((uint32_t)(v >> 32));
    pidx[tt] = (uint32_t)(v & 0xffffffffu);
  }

  float vt[TOPK], vm = -1e30f;
#pragma unroll
  for (int tt = 0; tt < TOPK; ++tt) {
    vt[tt] = -acosh_dev(zt[tt]) / TAU_;
    vm = fmaxf(vm, vt[tt]);
  }
  float ps = 0.0f;
#pragma unroll
  for (int tt = 0; tt < TOPK; ++tt) ps += expf(vt[tt] - vm);
  const float pos = vm + logf(ps);

#define CSWAP(a, b)                                                           \
  { const uint32_t mn = pidx[a] < pidx[b] ? pidx[a] : pidx[b];                \
    const uint32_t mx = pidx[a] < pidx[b] ? pidx[b] : pidx[a];                \
    pidx[a] = mn; pidx[b] = mx; }
  CSWAP(0, 1) CSWAP(3, 4) CSWAP(2, 4) CSWAP(2, 3) CSWAP(1, 4)
  CSWAP(0, 3) CSWAP(0, 2) CSWAP(1, 3) CSWAP(1, 2)
#undef CSWAP

  float v = -1e30f;
  if (lane < NEGS) {
    const uint32_t f = (uint32_t)i * (uint32_t)NEGS + (uint32_t)lane;
    uint32_t c = sample_idx(seed, f);
#pragma unroll
    for (int tt = 0; tt < TOPK; ++tt) c += (c >= pidx[tt]) ? 1u : 0u;
    if (c != (uint32_t)i) {
      const float4* xc = (const float4*)(X + (size_t)c * DIM);
      float dot = 0.0f;
#pragma unroll
      for (int k = 0; k < DIM / 4; ++k) {
        const float4 a = xi4[k];
        const float4 b = xc[k];
        dot = fmaf(a.x, b.x, dot); dot = fmaf(a.y, b.y, dot);
        dot = fmaf(a.z, b.z, dot); dot = fmaf(a.w, b.w, dot);
      }
      const float diff =
          fmaxf(ysq[m * N + i] + ysq[m * N + c] - 2.0f * dot, 0.0f);
      const float z = 1.0f + 2.0f * diff * inv[m * N + i] * inv[m * N + c];
      v = -acosh_dev(z) / TAU_;
    }
  }

  float vmax = v;
#pragma unroll
  for (int o = 32; o > 0; o >>= 1) vmax = fmaxf(vmax, __shfl_xor(vmax, o, 64));
  float e = expf(v - vmax);
  float ss = e;
#pragma unroll
  for (int o = 32; o > 0; o >>= 1) ss += __shfl_xor(ss, o, 64);
  if (lane == 0) rowres[m * N + i] = (vmax + logf(ss)) - pos;
}

// K3: deterministic final reduce (f64 accumulation), out = 0.01 * mean
__global__ __launch_bounds__(256) void k_reduce(const float* __restrict__ rowres,
                                                float* __restrict__ out) {
  __shared__ double sh[256];
  double s = 0.0;
  for (int idx = threadIdx.x; idx < 2 * N; idx += 256) s += (double)rowres[idx];
  sh[threadIdx.x] = s;
  __syncthreads();
  for (int o = 128; o > 0; o >>= 1) {
    if (threadIdx.x < o) sh[threadIdx.x] += sh[threadIdx.x + o];
    __syncthreads();
  }
  if (threadIdx.x == 0) out[0] = (float)(0.01 * (sh[0] / (double)N));
}

extern "C" void kernel_launch(void* const* d_in, const int* in_sizes, int n_in,
                              void* d_out, int out_size, void* d_ws,
                              size_t ws_size, hipStream_t stream) {
  const float* Xa = (const float*)d_in[0];   // audio_embeds
  const float* Xt = (const float*)d_in[1];   // text_embeds
  float* out = (float*)d_out;

  // ws layout (~2.5 MB): ysq[2N] | inv[2N] | top5[2N*5 u64] | rowres[2N] | XT[2][64][N]
  float* ysq = (float*)d_ws;
  float* inv = ysq + 2 * N;
  uint64_t* top5 = (uint64_t*)(inv + 2 * N);
  float* rowres = (float*)(top5 + (size_t)2 * N * TOPK);
  float* XT = rowres + 2 * N;

  k_pre<<<dim3(N / 64, 2), 256, 0, stream>>>(Xa, Xt, XT, ysq, inv);
  k_top5<<<dim3(N / 16, 2), 256, 0, stream>>>(Xa, Xt, XT, ysq, inv, top5);
  k_neg<<<dim3(N, 2), 64, 0, stream>>>(Xa, Xt, ysq, inv, top5, rowres);
  k_reduce<<<1, 256, 0, stream>>>(rowres, out);
}

// Round 4
// 135.505 us; speedup vs baseline: 5.3191x; 1.2093x over previous
//
#include <hip/hip_runtime.h>
#include <stdint.h>

#define JAX_PARTITIONABLE 1

constexpr int N = 4096;
constexpr int DIM = 64;
constexpr int TOPK = 5;
constexpr int NEGS = 20;
constexpr float TAU_ = 0.1f;
constexpr uint32_t SPAN = 4091u;   // N - TOPK
constexpr uint32_t MULT = 2309u;   // ((1<<16) % SPAN)^2 % SPAN

typedef __attribute__((ext_vector_type(8))) short bf16x8;
typedef __attribute__((ext_vector_type(4))) float f32x4;

__device__ __forceinline__ uint32_t rotl32(uint32_t v, int d) {
  return (v << d) | (v >> (32 - d));
}

// Threefry-2x32, 20 rounds, exactly as jax/_src/prng.py lowering.
__device__ __forceinline__ void threefry(uint32_t k0, uint32_t k1,
                                         uint32_t& x0, uint32_t& x1) {
  const uint32_t k2 = k0 ^ k1 ^ 0x1BD11BDAu;
  x0 += k0; x1 += k1;
#define TF_R(r) { x0 += x1; x1 = rotl32(x1, r); x1 ^= x0; }
  TF_R(13) TF_R(15) TF_R(26) TF_R(6)
  x0 += k1; x1 += k2 + 1u;
  TF_R(17) TF_R(29) TF_R(16) TF_R(24)
  x0 += k2; x1 += k0 + 2u;
  TF_R(13) TF_R(15) TF_R(26) TF_R(6)
  x0 += k0; x1 += k1 + 3u;
  TF_R(17) TF_R(29) TF_R(16) TF_R(24)
  x0 += k1; x1 += k2 + 4u;
  TF_R(13) TF_R(15) TF_R(26) TF_R(6)
  x0 += k2; x1 += k0 + 5u;
#undef TF_R
}

__device__ __forceinline__ uint32_t sample_idx(uint32_t seed, uint32_t f) {
#if JAX_PARTITIONABLE
  uint32_t a0 = 0u, a1 = 0u; threefry(0u, seed, a0, a1);   // k1 = enc(key,(0,0))
  uint32_t b0 = 0u, b1 = 1u; threefry(0u, seed, b0, b1);   // k2 = enc(key,(0,1))
  uint32_t h0 = 0u, h1 = f;  threefry(a0, a1, h0, h1);
  const uint32_t hi = h0 ^ h1;
  uint32_t l0 = 0u, l1 = f;  threefry(b0, b1, l0, l1);
  const uint32_t lo = l0 ^ l1;
#else
  uint32_t a0 = 0u, a1 = 2u; threefry(0u, seed, a0, a1);
  uint32_t c0 = 1u, c1 = 3u; threefry(0u, seed, c0, c1);
  const uint32_t HALF = (uint32_t)(N * NEGS / 2);
  uint32_t hi, lo;
  if (f < HALF) {
    uint32_t x0 = f, x1 = f + HALF; threefry(a0, c0, x0, x1); hi = x0;
    x0 = f; x1 = f + HALF;          threefry(a1, c1, x0, x1); lo = x0;
  } else {
    uint32_t x0 = f - HALF, x1 = f; threefry(a0, c0, x0, x1); hi = x1;
    x0 = f - HALF; x1 = f;          threefry(a1, c1, x0, x1); lo = x1;
  }
#endif
  return ((hi % SPAN) * MULT + (lo % SPAN)) % SPAN;
}

__device__ __forceinline__ float acosh_dev(float z) {
  return logf(z + sqrtf((z - 1.0f) * (z + 1.0f)));
}

__device__ __forceinline__ uint16_t f2bf(float f) {   // RNE f32 -> bf16
  const uint32_t u = __float_as_uint(f);
  return (uint16_t)((u + 0x7FFFu + ((u >> 16) & 1u)) >> 16);
}
__device__ __forceinline__ float bf2f(uint16_t h) {
  return __uint_as_float((uint32_t)h << 16);
}

// K_pre: per row: exact f32 norms + inv, and bf16 hi/lo split rows
// Xs layout: [mod][row][128 u16] = hi[64] | lo[64], row stride 256 B.
__global__ __launch_bounds__(64) void k_pre(const float* __restrict__ Xa,
                                            const float* __restrict__ Xt,
                                            uint16_t* __restrict__ Xs,
                                            float* __restrict__ ysq,
                                            float* __restrict__ inv) {
  const int m = blockIdx.y;                  // 0 = text, 1 = audio
  const float* __restrict__ X = (m == 0) ? Xt : Xa;
  const int i = blockIdx.x * 64 + threadIdx.x;
  const float* xr = X + (size_t)i * DIM;

  uint32_t hb[DIM / 2], lb[DIM / 2];
  float s = 0.0f;
#pragma unroll
  for (int u = 0; u < DIM / 4; ++u) {
    const float4 v = *(const float4*)(xr + 4 * u);
    s = fmaf(v.x, v.x, s); s = fmaf(v.y, v.y, s);
    s = fmaf(v.z, v.z, s); s = fmaf(v.w, v.w, s);
    const uint16_t h0 = f2bf(v.x), h1 = f2bf(v.y), h2 = f2bf(v.z), h3 = f2bf(v.w);
    const uint16_t l0 = f2bf(v.x - bf2f(h0)), l1 = f2bf(v.y - bf2f(h1));
    const uint16_t l2 = f2bf(v.z - bf2f(h2)), l3 = f2bf(v.w - bf2f(h3));
    hb[2 * u]     = (uint32_t)h0 | ((uint32_t)h1 << 16);
    hb[2 * u + 1] = (uint32_t)h2 | ((uint32_t)h3 << 16);
    lb[2 * u]     = (uint32_t)l0 | ((uint32_t)l1 << 16);
    lb[2 * u + 1] = (uint32_t)l2 | ((uint32_t)l3 << 16);
  }
  uint32_t* dst = (uint32_t*)(Xs + (size_t)(m * N + i) * 128);
#pragma unroll
  for (int w = 0; w < 8; ++w) {
    uint4 qh = { hb[4 * w], hb[4 * w + 1], hb[4 * w + 2], hb[4 * w + 3] };
    ((uint4*)dst)[w] = qh;
  }
#pragma unroll
  for (int w = 0; w < 8; ++w) {
    uint4 ql = { lb[4 * w], lb[4 * w + 1], lb[4 * w + 2], lb[4 * w + 3] };
    ((uint4*)dst)[8 + w] = ql;
  }
  ysq[m * N + i] = s;
  inv[m * N + i] = 1.0f / (1.0f - fminf(s, 1.0f));
}

// K1: MFMA pairwise-z + per-row top-5 partials.
// One wave per block. Wave owns 32 rows x 1024 cols (one col-quarter).
// dot = Ahi*Bhi + Ahi*Blo + Alo*Bhi via mfma_f32_16x16x32_bf16 (12 mfma/tile).
// grid (128 row-blocks, 4 quarters, 2 mods); B frags direct from global (L2).
__global__ __launch_bounds__(64) void k_top5(const uint16_t* __restrict__ Xs,
                                             const float* __restrict__ ysq,
                                             const float* __restrict__ inv,
                                             uint64_t* __restrict__ partial) {
  const int m = blockIdx.z;
  const int qq = blockIdx.y;
  const int i0 = blockIdx.x * 32;
  const int j0q = qq * 1024;
  const int mN = m * N;
  const uint16_t* __restrict__ Xm = Xs + (size_t)m * N * 128;
  const int l = (int)threadIdx.x;
  const int lc = l & 15;          // A-row / B-col lane index
  const int lk = l >> 4;          // k-chunk group
  const int lk4 = lk * 4;         // C-row base for this lane
  const int lk8 = lk * 8;         // u16 offset of this lane's 8 bf16

  // A fragments: af[row-tile][k-chunk][hi/lo]
  bf16x8 af[2][2][2];
#pragma unroll
  for (int rt = 0; rt < 2; ++rt)
#pragma unroll
    for (int c = 0; c < 2; ++c)
#pragma unroll
      for (int h = 0; h < 2; ++h)
        af[rt][c][h] = *(const bf16x8*)(Xm + (size_t)(i0 + rt * 16 + lc) * 128 +
                                        h * 64 + c * 32 + lk8);

  float xsq_r[2][4], inv_r[2][4];
#pragma unroll
  for (int rt = 0; rt < 2; ++rt)
#pragma unroll
    for (int p = 0; p < 4; ++p) {
      const int gi = i0 + rt * 16 + lk4 + p;
      xsq_r[rt][p] = ysq[mN + gi];
      inv_r[rt][p] = inv[mN + gi];
    }

  uint64_t t5[8][TOPK];
#pragma unroll
  for (int e = 0; e < 8; ++e)
#pragma unroll
    for (int t = 0; t < TOPK; ++t) t5[e][t] = ~0ull;

  const f32x4 zz = {0.0f, 0.0f, 0.0f, 0.0f};

#define LOADB(BF, YC, IC, T)                                                   \
  {                                                                            \
    const uint16_t* bp = Xm + (size_t)(j0q + (T) * 16 + lc) * 128 + lk8;       \
    BF[0][0] = *(const bf16x8*)(bp);                                           \
    BF[1][0] = *(const bf16x8*)(bp + 32);                                      \
    BF[0][1] = *(const bf16x8*)(bp + 64);                                      \
    BF[1][1] = *(const bf16x8*)(bp + 96);                                      \
    YC = ysq[mN + j0q + (T) * 16 + lc];                                        \
    IC = inv[mN + j0q + (T) * 16 + lc];                                        \
  }

#define MFMA_TILE(ACC, BF)                                                     \
  {                                                                            \
    ACC[0] = __builtin_amdgcn_mfma_f32_16x16x32_bf16(af[0][0][0], BF[0][0], zz, 0, 0, 0); \
    ACC[1] = __builtin_amdgcn_mfma_f32_16x16x32_bf16(af[1][0][0], BF[0][0], zz, 0, 0, 0); \
    ACC[0] = __builtin_amdgcn_mfma_f32_16x16x32_bf16(af[0][1][0], BF[1][0], ACC[0], 0, 0, 0); \
    ACC[1] = __builtin_amdgcn_mfma_f32_16x16x32_bf16(af[1][1][0], BF[1][0], ACC[1], 0, 0, 0); \
    ACC[0] = __builtin_amdgcn_mfma_f32_16x16x32_bf16(af[0][0][0], BF[0][1], ACC[0], 0, 0, 0); \
    ACC[1] = __builtin_amdgcn_mfma_f32_16x16x32_bf16(af[1][0][0], BF[0][1], ACC[1], 0, 0, 0); \
    ACC[0] = __builtin_amdgcn_mfma_f32_16x16x32_bf16(af[0][1][0], BF[1][1], ACC[0], 0, 0, 0); \
    ACC[1] = __builtin_amdgcn_mfma_f32_16x16x32_bf16(af[1][1][0], BF[1][1], ACC[1], 0, 0, 0); \
    ACC[0] = __builtin_amdgcn_mfma_f32_16x16x32_bf16(af[0][0][1], BF[0][0], ACC[0], 0, 0, 0); \
    ACC[1] = __builtin_amdgcn_mfma_f32_16x16x32_bf16(af[1][0][1], BF[0][0], ACC[1], 0, 0, 0); \
    ACC[0] = __builtin_amdgcn_mfma_f32_16x16x32_bf16(af[0][1][1], BF[1][0], ACC[0], 0, 0, 0); \
    ACC[1] = __builtin_amdgcn_mfma_f32_16x16x32_bf16(af[1][1][1], BF[1][0], ACC[1], 0, 0, 0); \
  }

#define EPILOG(T, ACC, YC, IC)                                                 \
  {                                                                            \
    const int gj = j0q + (T) * 16 + lc;                                        \
    _Pragma("unroll") for (int rt = 0; rt < 2; ++rt) {                         \
      _Pragma("unroll") for (int p = 0; p < 4; ++p) {                          \
        const int gi = i0 + rt * 16 + lk4 + p;                                 \
        const float diff =                                                     \
            fmaxf(xsq_r[rt][p] + (YC)-2.0f * ACC[rt][p], 0.0f);                \
        const float z = fmaf(2.0f * (diff * inv_r[rt][p]), (IC), 1.0f);        \
        uint64_t key = ((uint64_t)__float_as_uint(z) << 32) | (uint32_t)gj;    \
        const int e = rt * 4 + p;                                              \
        if (gi != gj && key < t5[e][TOPK - 1]) {                               \
          _Pragma("unroll") for (int tt = 0; tt < TOPK; ++tt) {                \
            const uint64_t cv = t5[e][tt];                                     \
            if (key < cv) { t5[e][tt] = key; key = cv; }                       \
          }                                                                    \
        }                                                                      \
      }                                                                        \
    }                                                                          \
  }

  bf16x8 bE[2][2], bO[2][2];
  float ycE, icE, ycO, icO;
  f32x4 accE[2], accO[2];

  LOADB(bE, ycE, icE, 0)
  LOADB(bO, ycO, icO, 1)
  MFMA_TILE(accE, bE)

#pragma unroll 1
  for (int t = 1; t < 64; t += 2) {
    const float ycEp = ycE, icEp = icE;
    if (t + 1 < 64) LOADB(bE, ycE, icE, t + 1)
    MFMA_TILE(accO, bO)
    EPILOG(t - 1, accE, ycEp, icEp)
    const float ycOp = ycO, icOp = icO;
    if (t + 2 < 64) LOADB(bO, ycO, icO, t + 2)
    if (t + 1 < 64) MFMA_TILE(accE, bE)
    EPILOG(t, accO, ycOp, icOp)
  }
#undef LOADB
#undef MFMA_TILE
#undef EPILOG

  // cross-lane merge: row r (0..31) has 16 contributor lists (lanes g*16+c,
  // g = (r&15)>>2 fixed by C layout: row = lk*4+p -> lanes with lk = r>>2 & 3)
  __shared__ uint64_t mbuf[32 * 81];   // stride 81 breaks bank alignment
#pragma unroll
  for (int rt = 0; rt < 2; ++rt)
#pragma unroll
    for (int p = 0; p < 4; ++p)
#pragma unroll
      for (int t = 0; t < TOPK; ++t)
        mbuf[(rt * 16 + lk4 + p) * 81 + lc * TOPK + t] = t5[rt * 4 + p][t];
  __syncthreads();

  if (l < 32) {
    uint64_t cur[TOPK];
#pragma unroll
    for (int t = 0; t < TOPK; ++t) cur[t] = mbuf[l * 81 + t];
    for (int c = 1; c < 16; ++c) {
      for (int t = 0; t < TOPK; ++t) {
        uint64_t key = mbuf[l * 81 + c * TOPK + t];
        if (key >= cur[TOPK - 1]) break;   // lists sorted ascending
#pragma unroll
        for (int u = 0; u < TOPK; ++u) {
          const uint64_t cv = cur[u];
          if (key < cv) { cur[u] = key; key = cv; }
        }
      }
    }
#pragma unroll
    for (int t = 0; t < TOPK; ++t)
      partial[((size_t)(m * 4 + qq) * N + i0 + l) * TOPK + t] = cur[t];
  }
}

// K2: merge quarter-partials -> top5; exact f32 pos_term recompute;
// threefry sampling + exact negative distances + logsumexp.
__global__ __launch_bounds__(64) void k_neg(const float* __restrict__ Xa,
                                            const float* __restrict__ Xt,
                                            const float* __restrict__ ysq,
                                            const float* __restrict__ inv,
                                            const uint64_t* __restrict__ partial,
                                            float* __restrict__ rowres) {
  const int m = blockIdx.y;
  const int i = blockIdx.x;
  const float* __restrict__ X = (m == 0) ? Xt : Xa;
  const uint32_t seed = (m == 0) ? 1u : 2u;  // key(1)=text, key(2)=audio
  const int lane = threadIdx.x;

  __shared__ float4 xi4[DIM / 4];
  __shared__ float posv[TOPK];
  if (lane < DIM / 4) xi4[lane] = ((const float4*)(X + (size_t)i * DIM))[lane];
  __syncthreads();

  // merge 4 sorted quarter lists (uniform across lanes)
  uint64_t cur[TOPK];
#pragma unroll
  for (int t = 0; t < TOPK; ++t)
    cur[t] = partial[((size_t)(m * 4) * N + i) * TOPK + t];
  for (int q = 1; q < 4; ++q) {
    for (int t = 0; t < TOPK; ++t) {
      uint64_t key = partial[((size_t)(m * 4 + q) * N + i) * TOPK + t];
      if (key >= cur[TOPK - 1]) break;
#pragma unroll
      for (int u = 0; u < TOPK; ++u) {
        const uint64_t cv = cur[u];
        if (key < cv) { cur[u] = key; key = cv; }
      }
    }
  }

  const float ysq_i = ysq[m * N + i];
  const float inv_i = inv[m * N + i];

  // lanes 32..36: exact f32 distance for the 5 selected positives
  if (lane >= 32 && lane < 32 + TOPK) {
    const int t = lane - 32;
    const uint32_t c = (uint32_t)(cur[t] & 0xffffffffu);
    const float4* xc = (const float4*)(X + (size_t)c * DIM);
    float dot = 0.0f;
#pragma unroll
    for (int k = 0; k < DIM / 4; ++k) {
      const float4 a = xi4[k];
      const float4 b = xc[k];
      dot = fmaf(a.x, b.x, dot); dot = fmaf(a.y, b.y, dot);
      dot = fmaf(a.z, b.z, dot); dot = fmaf(a.w, b.w, dot);
    }
    const float diff = fmaxf(ysq_i + ysq[m * N + c] - 2.0f * dot, 0.0f);
    const float z = 1.0f + 2.0f * diff * inv_i * inv[m * N + c];
    posv[t] = -acosh_dev(z) / TAU_;
  }

  uint32_t pidx[TOPK];
#pragma unroll
  for (int t = 0; t < TOPK; ++t) pidx[t] = (uint32_t)(cur[t] & 0xffffffffu);

#define CSWAP(a, b)                                                           \
  { const uint32_t mn = pidx[a] < pidx[b] ? pidx[a] : pidx[b];                \
    const uint32_t mx = pidx[a] < pidx[b] ? pidx[b] : pidx[a];                \
    pidx[a] = mn; pidx[b] = mx; }
  CSWAP(0, 1) CSWAP(3, 4) CSWAP(2, 4) CSWAP(2, 3) CSWAP(1, 4)
  CSWAP(0, 3) CSWAP(0, 2) CSWAP(1, 3) CSWAP(1, 2)
#undef CSWAP

  float v = -1e30f;
  if (lane < NEGS) {
    const uint32_t f = (uint32_t)i * (uint32_t)NEGS + (uint32_t)lane;
    uint32_t c = sample_idx(seed, f);
#pragma unroll
    for (int t = 0; t < TOPK; ++t) c += (c >= pidx[t]) ? 1u : 0u;
    if (c != (uint32_t)i) {
      const float4* xc = (const float4*)(X + (size_t)c * DIM);
      float dot = 0.0f;
#pragma unroll
      for (int k = 0; k < DIM / 4; ++k) {
        const float4 a = xi4[k];
        const float4 b = xc[k];
        dot = fmaf(a.x, b.x, dot); dot = fmaf(a.y, b.y, dot);
        dot = fmaf(a.z, b.z, dot); dot = fmaf(a.w, b.w, dot);
      }
      const float diff = fmaxf(ysq_i + ysq[m * N + c] - 2.0f * dot, 0.0f);
      const float z = 1.0f + 2.0f * diff * inv_i * inv[m * N + c];
      v = -acosh_dev(z) / TAU_;
    }
  }

  __syncthreads();   // posv visible

  float vmax = v;
#pragma unroll
  for (int o = 32; o > 0; o >>= 1) vmax = fmaxf(vmax, __shfl_xor(vmax, o, 64));
  float e = expf(v - vmax);
  float ss = e;
#pragma unroll
  for (int o = 32; o > 0; o >>= 1) ss += __shfl_xor(ss, o, 64);

  if (lane == 0) {
    float vm = -1e30f;
#pragma unroll
    for (int t = 0; t < TOPK; ++t) vm = fmaxf(vm, posv[t]);
    float ps = 0.0f;
#pragma unroll
    for (int t = 0; t < TOPK; ++t) ps += expf(posv[t] - vm);
    const float pos = vm + logf(ps);
    rowres[m * N + i] = (vmax + logf(ss)) - pos;
  }
}

// K3: deterministic final reduce (f64 accumulation), out = 0.01 * mean
__global__ __launch_bounds__(256) void k_reduce(const float* __restrict__ rowres,
                                                float* __restrict__ out) {
  __shared__ double sh[256];
  double s = 0.0;
  for (int idx = threadIdx.x; idx < 2 * N; idx += 256) s += (double)rowres[idx];
  sh[threadIdx.x] = s;
  __syncthreads();
  for (int o = 128; o > 0; o >>= 1) {
    if (threadIdx.x < o) sh[threadIdx.x] += sh[threadIdx.x + o];
    __syncthreads();
  }
  if (threadIdx.x == 0) out[0] = (float)(0.01 * (sh[0] / (double)N));
}

extern "C" void kernel_launch(void* const* d_in, const int* in_sizes, int n_in,
                              void* d_out, int out_size, void* d_ws,
                              size_t ws_size, hipStream_t stream) {
  const float* Xa = (const float*)d_in[0];   // audio_embeds
  const float* Xt = (const float*)d_in[1];   // text_embeds
  float* out = (float*)d_out;

  // ws layout (~3.4 MB): ysq[2N] | inv[2N] | partial[2*4*N*5 u64] | rowres[2N]
  //                      | Xs[2*N*128 u16]
  float* ysq = (float*)d_ws;
  float* inv = ysq + 2 * N;
  uint64_t* partial = (uint64_t*)(inv + 2 * N);
  float* rowres = (float*)(partial + (size_t)2 * 4 * N * TOPK);
  uint16_t* Xs = (uint16_t*)(rowres + 2 * N);

  k_pre<<<dim3(N / 64, 2), 64, 0, stream>>>(Xa, Xt, Xs, ysq, inv);
  k_top5<<<dim3(N / 32, 4, 2), 64, 0, stream>>>(Xs, ysq, inv, partial);
  k_neg<<<dim3(N, 2), 64, 0, stream>>>(Xa, Xt, ysq, inv, partial, rowres);
  k_reduce<<<1, 256, 0, stream>>>(rowres, out);
}